// Round 1
// baseline (1014.543 us; speedup 1.0000x reference)
//
#include <hip/hip_runtime.h>

#define TB_L 1024
#define TB_E 1024

static __device__ __forceinline__ float gelu_f(float x) {
  const float c0 = 0.7978845608028654f;
  const float c1 = 0.044715f;
  float x3 = x * x * x;
  return 0.5f * x * (1.0f + tanhf(c0 * (x + c1 * x3)));
}

// One block per row: RMS norm over E=1024, 256 threads x float4.
__global__ __launch_bounds__(256) void rms_kernel(const float* __restrict__ x,
                                                  const float* __restrict__ w,
                                                  float* __restrict__ out) {
  const int row = blockIdx.x;
  const int tid = threadIdx.x;
  const float4 v = *(const float4*)(x + (size_t)row * TB_E + tid * 4);
  float s = v.x * v.x + v.y * v.y + v.z * v.z + v.w * v.w;
#pragma unroll
  for (int off = 32; off > 0; off >>= 1) s += __shfl_down(s, off);
  __shared__ float red[4];
  if ((tid & 63) == 0) red[tid >> 6] = s;
  __syncthreads();
  const float tot = red[0] + red[1] + red[2] + red[3];
  const float scale = rsqrtf(tot * (1.0f / TB_E) + 1e-6f);
  const float4 wv = *(const float4*)(w + tid * 4);
  float4 o;
  o.x = v.x * scale * wv.x;
  o.y = v.y * scale * wv.y;
  o.z = v.z * scale * wv.z;
  o.w = v.w * scale * wv.w;
  *(float4*)(out + (size_t)row * TB_E + tid * 4) = o;
}

// C = act(A@B + bias) [+ res]; A: MxK row-major, B: KxN row-major.
// 64x64 tile, BK=16, 256 threads, 4x4 per thread.
__global__ __launch_bounds__(256) void gemm_kernel(const float* __restrict__ A,
                                                   const float* __restrict__ B,
                                                   const float* __restrict__ bias,
                                                   const float* __restrict__ res,
                                                   float* __restrict__ C,
                                                   int M, int N, int K, int do_gelu) {
  const int tid = threadIdx.x;
  const int tx = tid & 15, ty = tid >> 4;
  const int m0 = blockIdx.y * 64, n0 = blockIdx.x * 64;
  __shared__ float As[16][68];  // As[k][m], stride 68 keeps float4 16B-aligned
  __shared__ float Bs[16][68];  // Bs[k][n]
  float acc[4][4] = {{0.f}};
  const int lar = tid >> 2;         // A load row (0..63)
  const int lac = (tid & 3) * 4;    // A load col (0..12)
  const int lbr = tid >> 4;         // B load row (0..15)
  const int lbc = (tid & 15) * 4;   // B load col (0..60)
  const float* Aptr = A + (size_t)(m0 + lar) * K + lac;
  const float* Bptr = B + (size_t)lbr * N + n0 + lbc;

  for (int k0 = 0; k0 < K; k0 += 16) {
    const float4 a4 = *(const float4*)(Aptr + k0);
    const float4 b4 = *(const float4*)(Bptr + (size_t)k0 * N);
    __syncthreads();  // previous iteration's LDS reads complete
    As[lac + 0][lar] = a4.x;
    As[lac + 1][lar] = a4.y;
    As[lac + 2][lar] = a4.z;
    As[lac + 3][lar] = a4.w;
    *(float4*)&Bs[lbr][lbc] = b4;
    __syncthreads();
#pragma unroll
    for (int kk = 0; kk < 16; ++kk) {
      const float4 av = *(const float4*)&As[kk][ty * 4];
      const float4 bv = *(const float4*)&Bs[kk][tx * 4];
      const float a[4] = {av.x, av.y, av.z, av.w};
      const float b[4] = {bv.x, bv.y, bv.z, bv.w};
#pragma unroll
      for (int i = 0; i < 4; ++i)
#pragma unroll
        for (int j = 0; j < 4; ++j) acc[i][j] += a[i] * b[j];
    }
  }

#pragma unroll
  for (int i = 0; i < 4; ++i) {
    const int row = m0 + ty * 4 + i;
    const int col = n0 + tx * 4;
    float v[4];
#pragma unroll
    for (int j = 0; j < 4; ++j) {
      v[j] = acc[i][j] + bias[col + j];
      if (do_gelu) v[j] = gelu_f(v[j]);
    }
    if (res) {
      const float4 r4 = *(const float4*)(res + (size_t)row * N + col);
      v[0] += r4.x; v[1] += r4.y; v[2] += r4.z; v[3] += r4.w;
    }
    float4 o;
    o.x = v[0]; o.y = v[1]; o.z = v[2]; o.w = v[3];
    *(float4*)(C + (size_t)row * N + col) = o;
  }
}

// Cosformer causal linear attention, quadratic flash-style form:
// s_ij = (relu(q_i).relu(k_j)) * cos(pi/2 * (i-j)/L),  j <= i
// out_i = sum_j s_ij v_j / (sum_j s_ij + eps)
// grid: (16 i-tiles, 32 b*h), block 256. qkv layout: [b, l, {q,k,v} x (h,d)]
__global__ __launch_bounds__(256) void attn_kernel(const float* __restrict__ qkv,
                                                   float* __restrict__ out) {
  const int it = blockIdx.x;
  const int bh = blockIdx.y;
  const int b = bh >> 4, h = bh & 15;
  const int tid = threadIdx.x;
  const int i0 = it * 64;
  __shared__ float sk[64 * 64];  // swizzled: k[j][d ^ (j&48)]
  __shared__ float sv[64 * 64];  // plain v[j][e]
  __shared__ float sq[64 * 64];  // q staging (rotate-swizzled), then score tile

  const float* base = qkv + (size_t)b * (TB_L * 3072) + h * 64;

  // stage Q tile (relu), rotate-swizzle col' = (c + 4r) & 63 (bank-spread reads)
  for (int rep = 0; rep < 4; ++rep) {
    const int idx = rep * 1024 + tid * 4;
    const int r = idx >> 6, c = idx & 63;
    const float4 q4 = *(const float4*)(base + (size_t)(i0 + r) * 3072 + c);
    const int cc = (c + 4 * r) & 63;
    float4 t;
    t.x = fmaxf(q4.x, 0.f); t.y = fmaxf(q4.y, 0.f);
    t.z = fmaxf(q4.z, 0.f); t.w = fmaxf(q4.w, 0.f);
    *(float4*)&sq[r * 64 + cc] = t;
  }
  __syncthreads();

  const int ti = tid >> 2;   // local i row (0..63)
  const int tc = tid & 3;
  const int jb = tc * 16;    // this thread's j-range for scores / e-range for PV
  float qreg[64];
#pragma unroll
  for (int d = 0; d < 64; d += 4) {
    const float4 q4 = *(const float4*)&sq[ti * 64 + ((d + 4 * ti) & 63)];
    qreg[d] = q4.x; qreg[d + 1] = q4.y; qreg[d + 2] = q4.z; qreg[d + 3] = q4.w;
  }
  float acc[16];
#pragma unroll
  for (int m = 0; m < 16; ++m) acc[m] = 0.f;
  float norm = 0.f;
  const float PH = 1.5339807878856412e-3f;  // pi/2/1024
  const int ig = i0 + ti;

  for (int jt = 0; jt <= it; ++jt) {
    const int j0 = jt * 64;
    __syncthreads();  // previous tile's LDS reads complete
    for (int rep = 0; rep < 4; ++rep) {
      const int idx = rep * 1024 + tid * 4;
      const int r = idx >> 6, c = idx & 63;
      const float4 k4 = *(const float4*)(base + (size_t)(j0 + r) * 3072 + 1024 + c);
      const float4 v4 = *(const float4*)(base + (size_t)(j0 + r) * 3072 + 2048 + c);
      const int cs = c ^ (r & 48);
      float4 t;
      t.x = fmaxf(k4.x, 0.f); t.y = fmaxf(k4.y, 0.f);
      t.z = fmaxf(k4.z, 0.f); t.w = fmaxf(k4.w, 0.f);
      *(float4*)&sk[r * 64 + cs] = t;
      *(float4*)&sv[r * 64 + c] = v4;
    }
    __syncthreads();
    const bool diag = (jt == it);
    // scores: thread computes row ti, 16 j's
#pragma unroll 4
    for (int m = 0; m < 16; ++m) {
      const int j = jb + m;
      const int sw = j & 48;
      float dot = 0.f;
#pragma unroll
      for (int d = 0; d < 64; d += 4) {
        const float4 k4 = *(const float4*)&sk[j * 64 + (d ^ sw)];
        dot += qreg[d] * k4.x + qreg[d + 1] * k4.y +
               qreg[d + 2] * k4.z + qreg[d + 3] * k4.w;
      }
      float sval = dot * cosf(PH * (float)(ig - (j0 + j)));
      if (diag && j > ti) sval = 0.f;
      sq[ti * 64 + (j ^ (ti & 15))] = sval;  // XOR-swizzled score tile
    }
    __syncthreads();
    // PV: thread accumulates row ti, e in [jb, jb+16)
#pragma unroll 4
    for (int j = 0; j < 64; ++j) {
      const float sval = sq[ti * 64 + (j ^ (ti & 15))];
      norm += sval;  // all 4 threads of the row compute identical full row-sum
      const float* vr = &sv[j * 64 + jb];
#pragma unroll
      for (int mm = 0; mm < 16; mm += 4) {
        const float4 v4 = *(const float4*)(vr + mm);
        acc[mm] += sval * v4.x;
        acc[mm + 1] += sval * v4.y;
        acc[mm + 2] += sval * v4.z;
        acc[mm + 3] += sval * v4.w;
      }
    }
  }
  const float inv = 1.0f / (norm + 1e-6f);
  float* orow = out + (size_t)(b * TB_L + i0 + ti) * TB_E + h * 64 + jb;
#pragma unroll
  for (int mm = 0; mm < 16; mm += 4) {
    float4 o;
    o.x = acc[mm] * inv; o.y = acc[mm + 1] * inv;
    o.z = acc[mm + 2] * inv; o.w = acc[mm + 3] * inv;
    *(float4*)(orow + mm) = o;
  }
}

extern "C" void kernel_launch(void* const* d_in, const int* in_sizes, int n_in,
                              void* d_out, int out_size, void* d_ws, size_t ws_size,
                              hipStream_t stream) {
  const float* x     = (const float*)d_in[0];
  const float* qkv_w = (const float*)d_in[1];
  const float* qkv_b = (const float*)d_in[2];
  const float* out_w = (const float*)d_in[3];
  const float* out_b = (const float*)d_in[4];
  const float* n1w   = (const float*)d_in[5];
  const float* n2w   = (const float*)d_in[6];
  const float* w1    = (const float*)d_in[7];
  const float* b1    = (const float*)d_in[8];
  const float* w2    = (const float*)d_in[9];
  const float* b2    = (const float*)d_in[10];
  float* ws = (float*)d_ws;

  // workspace layout (floats):
  // [0, 8388608)          qkv (2048x3072) ... later reused as g (2048x4096)
  // [8388608, 10485760)   xn / hn (2048x1024)
  // [10485760, 12582912)  attn_out (2048x1024)
  // [12582912, 14680064)  h (2048x1024)
  float* qkv  = ws;
  float* g    = ws;
  float* xn   = ws + 8388608;
  float* attn = ws + 10485760;
  float* h    = ws + 12582912;
  float* out  = (float*)d_out;
  const int M = 2048;

  rms_kernel<<<dim3(M), dim3(256), 0, stream>>>(x, n1w, xn);
  gemm_kernel<<<dim3(3072 / 64, M / 64), dim3(256), 0, stream>>>(
      xn, qkv_w, qkv_b, nullptr, qkv, M, 3072, 1024, 0);
  attn_kernel<<<dim3(16, 32), dim3(256), 0, stream>>>(qkv, attn);
  gemm_kernel<<<dim3(1024 / 64, M / 64), dim3(256), 0, stream>>>(
      attn, out_w, out_b, x, h, M, 1024, 1024, 0);
  rms_kernel<<<dim3(M), dim3(256), 0, stream>>>(h, n2w, xn);
  gemm_kernel<<<dim3(4096 / 64, M / 64), dim3(256), 0, stream>>>(
      xn, w1, b1, nullptr, g, M, 4096, 1024, 1);
  gemm_kernel<<<dim3(1024 / 64, M / 64), dim3(256), 0, stream>>>(
      g, w2, b2, h, out, M, 1024, 4096, 0);
}

// Round 2
// 458.639 us; speedup vs baseline: 2.2121x; 2.2121x over previous
//
#include <hip/hip_runtime.h>

#define TB_L 1024
#define TB_E 1024

typedef __attribute__((ext_vector_type(8))) short bf16x8;
typedef __attribute__((ext_vector_type(8))) unsigned short u16x8;
typedef __attribute__((ext_vector_type(4))) float floatx4;

#define AS1(p) ((const __attribute__((address_space(1))) void*)(p))
#define AS3(p) ((__attribute__((address_space(3))) void*)(p))

static __device__ __forceinline__ unsigned short f2bf(float x) {
  union { float f; unsigned u; } c; c.f = x;
  unsigned r = c.u + 0x7fff + ((c.u >> 16) & 1);
  return (unsigned short)(r >> 16);
}
static __device__ __forceinline__ float bf2f(unsigned short h) {
  union { unsigned u; float f; } c; c.u = ((unsigned)h) << 16;
  return c.f;
}
static __device__ __forceinline__ float gelu_f(float x) {
  const float c0 = 0.7978845608028654f;
  const float c1 = 0.044715f;
  float x3 = x * x * x;
  return 0.5f * x * (1.0f + tanhf(c0 * (x + c1 * x3)));
}

// RMS norm over E=1024, one block per row, bf16 output.
__global__ __launch_bounds__(256) void rms_kernel(const float* __restrict__ x,
                                                  const float* __restrict__ w,
                                                  unsigned short* __restrict__ out) {
  const int row = blockIdx.x;
  const int tid = threadIdx.x;
  const float4 v = *(const float4*)(x + (size_t)row * TB_E + tid * 4);
  float s = v.x * v.x + v.y * v.y + v.z * v.z + v.w * v.w;
#pragma unroll
  for (int off = 32; off > 0; off >>= 1) s += __shfl_down(s, off);
  __shared__ float red[4];
  if ((tid & 63) == 0) red[tid >> 6] = s;
  __syncthreads();
  const float tot = red[0] + red[1] + red[2] + red[3];
  const float scale = rsqrtf(tot * (1.0f / TB_E) + 1e-6f);
  const float4 wv = *(const float4*)(w + tid * 4);
  ushort4 o;
  o.x = f2bf(v.x * scale * wv.x);
  o.y = f2bf(v.y * scale * wv.y);
  o.z = f2bf(v.z * scale * wv.z);
  o.w = f2bf(v.w * scale * wv.w);
  *(ushort4*)(out + (size_t)row * TB_E + tid * 4) = o;
}

// Transpose + bf16 convert: in K x N fp32 (row-major) -> out N x K bf16.
__global__ __launch_bounds__(256) void transpose_bf16(const float* __restrict__ in,
                                                      unsigned short* __restrict__ out,
                                                      int K, int N) {
  __shared__ float t[64][65];
  const int tid = threadIdx.x;
  const int n0 = blockIdx.x * 64, k0 = blockIdx.y * 64;
#pragma unroll
  for (int rep = 0; rep < 4; ++rep) {
    const int r = rep * 16 + (tid >> 4);
    const int c = (tid & 15) * 4;
    const float4 v = *(const float4*)(in + (size_t)(k0 + r) * N + n0 + c);
    t[r][c] = v.x; t[r][c + 1] = v.y; t[r][c + 2] = v.z; t[r][c + 3] = v.w;
  }
  __syncthreads();
#pragma unroll
  for (int rep = 0; rep < 4; ++rep) {
    const int n = rep * 16 + (tid >> 4);
    const int k = (tid & 15) * 4;
    ushort4 o;
    o.x = f2bf(t[k + 0][n]);
    o.y = f2bf(t[k + 1][n]);
    o.z = f2bf(t[k + 2][n]);
    o.w = f2bf(t[k + 3][n]);
    *(ushort4*)(out + (size_t)(n0 + n) * K + k0 + k) = o;
  }
}

// bf16 MFMA GEMM: C = act(A@B + bias) [+ res]
// A: M x K bf16 row-major.  Bt: N x K bf16 (k-contiguous).
// 256 threads = 4 waves arranged (BM/WM) x (BN/WN); per-wave WM x WN output.
// LDS: As[BM][32], Bs[BN][32] bf16, staged with global_load_lds width=16
// (layout = exact lane order: strip s of 16 rows at byte s*1024 + lane*16).
template <int BM, int BN, int WM, int WN, bool GELU>
__global__ __launch_bounds__(256) void gemm_bf16(
    const unsigned short* __restrict__ A, const unsigned short* __restrict__ Bt,
    const float* __restrict__ bias, const float* __restrict__ res,
    float* __restrict__ Cf, unsigned short* __restrict__ Cb,
    int M, int N, int K) {
  constexpr int WCOLS = BN / WN;
  constexpr int LA = BM / 64;
  constexpr int LB = BN / 64;
  constexpr int MT = WM / 16;
  constexpr int NT = WN / 16;
  __shared__ __align__(16) unsigned short As[BM * 32];
  __shared__ __align__(16) unsigned short Bs[BN * 32];
  const int tid = threadIdx.x;
  const int wid = tid >> 6, lane = tid & 63;
  const int m0 = blockIdx.y * BM, n0 = blockIdx.x * BN;
  const int mbase = (wid / WCOLS) * WM, nbase = (wid % WCOLS) * WN;

  floatx4 acc[MT][NT];
#pragma unroll
  for (int i = 0; i < MT; ++i)
#pragma unroll
    for (int j = 0; j < NT; ++j) {
      floatx4 z = {0.f, 0.f, 0.f, 0.f};
      acc[i][j] = z;
    }

  const int srow = lane >> 2;       // 0..15 within strip
  const int scol = (lane & 3) * 8;  // k element offset
  const unsigned short* Ag = A + (size_t)m0 * K;
  const unsigned short* Bg = Bt + (size_t)n0 * K;
  const char* Ab = (const char*)As;
  const char* Bb = (const char*)Bs;
  const int fr = (lane & 15);       // fragment row/col within 16
  const int fk = (lane >> 4) * 16;  // byte offset of 8-elem k chunk

  for (int k0 = 0; k0 < K; k0 += 32) {
    __syncthreads();
#pragma unroll
    for (int j = 0; j < LA; ++j) {
      const int strip = j * 4 + wid;
      __builtin_amdgcn_global_load_lds(
          AS1(Ag + (size_t)(strip * 16 + srow) * K + k0 + scol),
          AS3((char*)As + strip * 1024), 16, 0, 0);
    }
#pragma unroll
    for (int j = 0; j < LB; ++j) {
      const int strip = j * 4 + wid;
      __builtin_amdgcn_global_load_lds(
          AS1(Bg + (size_t)(strip * 16 + srow) * K + k0 + scol),
          AS3((char*)Bs + strip * 1024), 16, 0, 0);
    }
    __syncthreads();
    bf16x8 af[MT], bfr[NT];
#pragma unroll
    for (int i = 0; i < MT; ++i)
      af[i] = *(const bf16x8*)(Ab + (mbase + i * 16 + fr) * 64 + fk);
#pragma unroll
    for (int j = 0; j < NT; ++j)
      bfr[j] = *(const bf16x8*)(Bb + (nbase + j * 16 + fr) * 64 + fk);
#pragma unroll
    for (int i = 0; i < MT; ++i)
#pragma unroll
      for (int j = 0; j < NT; ++j)
        acc[i][j] = __builtin_amdgcn_mfma_f32_16x16x32_bf16(af[i], bfr[j],
                                                            acc[i][j], 0, 0, 0);
  }

  // C/D layout: n = lane&15, m = (lane>>4)*4 + r
  const int mr = (lane >> 4) * 4;
  const int nc = lane & 15;
#pragma unroll
  for (int i = 0; i < MT; ++i)
#pragma unroll
    for (int j = 0; j < NT; ++j) {
      const int n = n0 + nbase + j * 16 + nc;
      const float bv = bias[n];
#pragma unroll
      for (int r = 0; r < 4; ++r) {
        const int m = m0 + mbase + i * 16 + mr + r;
        float v = acc[i][j][r] + bv;
        if (GELU) v = gelu_f(v);
        if (res) v += res[(size_t)m * N + n];
        if (Cf) Cf[(size_t)m * N + n] = v;
        if (Cb) Cb[(size_t)m * N + n] = f2bf(v);
      }
    }
}

// Cosformer causal linear attention (quadratic flash-style), bf16 in/out.
// s_ij = (relu(q_i).relu(k_j)) * cos(pi/2*(i-j)/L), j<=i; out_i = sum s v / (sum s + eps)
__global__ __launch_bounds__(256) void attn_kernel(const unsigned short* __restrict__ qkv,
                                                   unsigned short* __restrict__ out) {
  const int it = blockIdx.x;
  const int bh = blockIdx.y;
  const int b = bh >> 4, h = bh & 15;
  const int tid = threadIdx.x;
  const int i0 = it * 64;
  __shared__ __align__(16) float sk[64 * 64];
  __shared__ __align__(16) float sv[64 * 64];
  __shared__ __align__(16) float sq[64 * 64];

  const unsigned short* base = qkv + (size_t)b * (TB_L * 3072) + h * 64;

  // stage Q (relu), rotate-swizzle col' = (c + 4r) & 63 per 4-chunk
#pragma unroll
  for (int rep = 0; rep < 2; ++rep) {
    const int idx = rep * 2048 + tid * 8;
    const int r = idx >> 6, c = idx & 63;
    const u16x8 q8 = *(const u16x8*)(base + (size_t)(i0 + r) * 3072 + c);
    float f[8];
#pragma unroll
    for (int z = 0; z < 8; ++z) f[z] = fmaxf(bf2f(q8[z]), 0.f);
    const int cc0 = (c + 4 * r) & 63;
    const int cc1 = (c + 4 + 4 * r) & 63;
    float4 t0 = {f[0], f[1], f[2], f[3]};
    float4 t1 = {f[4], f[5], f[6], f[7]};
    *(float4*)&sq[r * 64 + cc0] = t0;
    *(float4*)&sq[r * 64 + cc1] = t1;
  }
  __syncthreads();

  const int ti = tid >> 2;
  const int tc = tid & 3;
  const int jb = tc * 16;
  float qreg[64];
#pragma unroll
  for (int d = 0; d < 64; d += 4) {
    const float4 q4 = *(const float4*)&sq[ti * 64 + ((d + 4 * ti) & 63)];
    qreg[d] = q4.x; qreg[d + 1] = q4.y; qreg[d + 2] = q4.z; qreg[d + 3] = q4.w;
  }
  float acc[16];
#pragma unroll
  for (int m = 0; m < 16; ++m) acc[m] = 0.f;
  float norm = 0.f;
  const float PH = 1.5339807878856412e-3f;  // pi/2/1024
  const int ig = i0 + ti;

  for (int jt = 0; jt <= it; ++jt) {
    const int j0 = jt * 64;
    __syncthreads();
#pragma unroll
    for (int rep = 0; rep < 2; ++rep) {
      const int idx = rep * 2048 + tid * 8;
      const int r = idx >> 6, c = idx & 63;
      const u16x8 k8 = *(const u16x8*)(base + (size_t)(j0 + r) * 3072 + 1024 + c);
      const u16x8 v8 = *(const u16x8*)(base + (size_t)(j0 + r) * 3072 + 2048 + c);
      float kf[8], vf[8];
#pragma unroll
      for (int z = 0; z < 8; ++z) {
        kf[z] = fmaxf(bf2f(k8[z]), 0.f);
        vf[z] = bf2f(v8[z]);
      }
      const int cs = c ^ (r & 48);
      float4 ta = {kf[0], kf[1], kf[2], kf[3]};
      float4 tb = {kf[4], kf[5], kf[6], kf[7]};
      *(float4*)&sk[r * 64 + cs] = ta;
      *(float4*)&sk[r * 64 + cs + 4] = tb;
      float4 va = {vf[0], vf[1], vf[2], vf[3]};
      float4 vb = {vf[4], vf[5], vf[6], vf[7]};
      *(float4*)&sv[r * 64 + c] = va;
      *(float4*)&sv[r * 64 + c + 4] = vb;
    }
    __syncthreads();
    const bool diag = (jt == it);
#pragma unroll 4
    for (int m = 0; m < 16; ++m) {
      const int j = jb + m;
      const int sw = j & 48;
      float dot = 0.f;
#pragma unroll
      for (int d = 0; d < 64; d += 4) {
        const float4 k4 = *(const float4*)&sk[j * 64 + (d ^ sw)];
        dot += qreg[d] * k4.x + qreg[d + 1] * k4.y +
               qreg[d + 2] * k4.z + qreg[d + 3] * k4.w;
      }
      float sval = dot * cosf(PH * (float)(ig - (j0 + j)));
      if (diag && j > ti) sval = 0.f;
      sq[ti * 64 + (j ^ (ti & 15))] = sval;
    }
    __syncthreads();
#pragma unroll 4
    for (int j = 0; j < 64; ++j) {
      const float sval = sq[ti * 64 + (j ^ (ti & 15))];
      norm += sval;
      const float* vr = &sv[j * 64 + jb];
#pragma unroll
      for (int mm = 0; mm < 16; mm += 4) {
        const float4 v4 = *(const float4*)(vr + mm);
        acc[mm] += sval * v4.x;
        acc[mm + 1] += sval * v4.y;
        acc[mm + 2] += sval * v4.z;
        acc[mm + 3] += sval * v4.w;
      }
    }
  }
  const float inv = 1.0f / (norm + 1e-6f);
  unsigned short* orow = out + (size_t)(b * TB_L + i0 + ti) * TB_E + h * 64 + jb;
#pragma unroll
  for (int mm = 0; mm < 16; mm += 4) {
    ushort4 o;
    o.x = f2bf(acc[mm] * inv);
    o.y = f2bf(acc[mm + 1] * inv);
    o.z = f2bf(acc[mm + 2] * inv);
    o.w = f2bf(acc[mm + 3] * inv);
    *(ushort4*)(orow + mm) = o;
  }
}

extern "C" void kernel_launch(void* const* d_in, const int* in_sizes, int n_in,
                              void* d_out, int out_size, void* d_ws, size_t ws_size,
                              hipStream_t stream) {
  const float* x     = (const float*)d_in[0];
  const float* qkv_w = (const float*)d_in[1];
  const float* qkv_b = (const float*)d_in[2];
  const float* out_w = (const float*)d_in[3];
  const float* out_b = (const float*)d_in[4];
  const float* n1w   = (const float*)d_in[5];
  const float* n2w   = (const float*)d_in[6];
  const float* w1    = (const float*)d_in[7];
  const float* b1    = (const float*)d_in[8];
  const float* w2    = (const float*)d_in[9];
  const float* b2    = (const float*)d_in[10];

  char* wsb = (char*)d_ws;
  // region1 (16MB): qkv bf16 (2048x3072) then g bf16 (2048x4096)
  unsigned short* qkvb  = (unsigned short*)wsb;
  unsigned short* g     = (unsigned short*)wsb;
  unsigned short* xnb   = (unsigned short*)(wsb + 16777216);  // also hn
  unsigned short* attnb = (unsigned short*)(wsb + 20971520);
  float*          h     = (float*)(wsb + 25165824);
  unsigned short* qkvwt = (unsigned short*)(wsb + 33554432);  // 3072x1024
  unsigned short* outwt = (unsigned short*)(wsb + 39845888);  // 1024x1024
  unsigned short* w1t   = (unsigned short*)(wsb + 41943040);  // 4096x1024
  unsigned short* w2t   = (unsigned short*)(wsb + 50331648);  // 1024x4096
  float* out = (float*)d_out;
  const int M = 2048;

  transpose_bf16<<<dim3(3072 / 64, 1024 / 64), 256, 0, stream>>>(qkv_w, qkvwt, 1024, 3072);
  transpose_bf16<<<dim3(1024 / 64, 1024 / 64), 256, 0, stream>>>(out_w, outwt, 1024, 1024);
  transpose_bf16<<<dim3(4096 / 64, 1024 / 64), 256, 0, stream>>>(w1, w1t, 1024, 4096);
  transpose_bf16<<<dim3(1024 / 64, 4096 / 64), 256, 0, stream>>>(w2, w2t, 4096, 1024);

  rms_kernel<<<dim3(M), 256, 0, stream>>>(x, n1w, xnb);
  gemm_bf16<64, 128, 64, 32, false><<<dim3(3072 / 128, M / 64), 256, 0, stream>>>(
      xnb, qkvwt, qkv_b, nullptr, nullptr, qkvb, M, 3072, 1024);
  attn_kernel<<<dim3(16, 32), 256, 0, stream>>>(qkvb, attnb);
  gemm_bf16<64, 64, 32, 32, false><<<dim3(1024 / 64, M / 64), 256, 0, stream>>>(
      attnb, outwt, out_b, x, h, nullptr, M, 1024, 1024);
  rms_kernel<<<dim3(M), 256, 0, stream>>>(h, n2w, xnb);
  gemm_bf16<128, 128, 64, 64, true><<<dim3(4096 / 128, M / 128), 256, 0, stream>>>(
      xnb, w1t, b1, nullptr, nullptr, g, M, 4096, 1024);
  gemm_bf16<64, 64, 32, 32, false><<<dim3(1024 / 64, M / 64), 256, 0, stream>>>(
      g, w2t, b2, h, out, nullptr, M, 1024, 4096);
}

// Round 3
// 302.412 us; speedup vs baseline: 3.3548x; 1.5166x over previous
//
#include <hip/hip_runtime.h>

#define TB_L 1024
#define TB_E 1024

typedef __attribute__((ext_vector_type(8))) short bf16x8;
typedef __attribute__((ext_vector_type(8))) unsigned short u16x8;
typedef __attribute__((ext_vector_type(4))) float floatx4;

#define AS1(p) ((const __attribute__((address_space(1))) void*)(p))
#define AS3(p) ((__attribute__((address_space(3))) void*)(p))

static __device__ __forceinline__ unsigned short f2bf(float x) {
  union { float f; unsigned u; } c; c.f = x;
  unsigned r = c.u + 0x7fff + ((c.u >> 16) & 1);
  return (unsigned short)(r >> 16);
}
static __device__ __forceinline__ float bf2f(unsigned short h) {
  union { unsigned u; float f; } c; c.u = ((unsigned)h) << 16;
  return c.f;
}
static __device__ __forceinline__ float gelu_f(float x) {
  const float c0 = 0.7978845608028654f;
  const float c1 = 0.044715f;
  float x3 = x * x * x;
  return 0.5f * x * (1.0f + tanhf(c0 * (x + c1 * x3)));
}

// swizzled LDS addressing for 64-row x 128-byte tiles: 16B chunk XOR'd by row hash
static __device__ __forceinline__ int swz(int row, int bytecol) {
  return row * 128 +
         ((((bytecol >> 4) ^ ((row + (row >> 3)) & 7)) << 4) | (bytecol & 15));
}

// RMS norm over E=1024, one block per row, bf16 output.
__global__ __launch_bounds__(256) void rms_kernel(const float* __restrict__ x,
                                                  const float* __restrict__ w,
                                                  unsigned short* __restrict__ out) {
  const int row = blockIdx.x;
  const int tid = threadIdx.x;
  const float4 v = *(const float4*)(x + (size_t)row * TB_E + tid * 4);
  float s = v.x * v.x + v.y * v.y + v.z * v.z + v.w * v.w;
#pragma unroll
  for (int off = 32; off > 0; off >>= 1) s += __shfl_down(s, off);
  __shared__ float red[4];
  if ((tid & 63) == 0) red[tid >> 6] = s;
  __syncthreads();
  const float tot = red[0] + red[1] + red[2] + red[3];
  const float scale = rsqrtf(tot * (1.0f / TB_E) + 1e-6f);
  const float4 wv = *(const float4*)(w + tid * 4);
  ushort4 o;
  o.x = f2bf(v.x * scale * wv.x);
  o.y = f2bf(v.y * scale * wv.y);
  o.z = f2bf(v.z * scale * wv.z);
  o.w = f2bf(v.w * scale * wv.w);
  *(ushort4*)(out + (size_t)row * TB_E + tid * 4) = o;
}

// Transpose + bf16 convert: in K x N fp32 (row-major) -> out N x K bf16.
__global__ __launch_bounds__(256) void transpose_bf16(const float* __restrict__ in,
                                                      unsigned short* __restrict__ out,
                                                      int K, int N) {
  __shared__ float t[64][65];
  const int tid = threadIdx.x;
  const int n0 = blockIdx.x * 64, k0 = blockIdx.y * 64;
#pragma unroll
  for (int rep = 0; rep < 4; ++rep) {
    const int r = rep * 16 + (tid >> 4);
    const int c = (tid & 15) * 4;
    const float4 v = *(const float4*)(in + (size_t)(k0 + r) * N + n0 + c);
    t[r][c] = v.x; t[r][c + 1] = v.y; t[r][c + 2] = v.z; t[r][c + 3] = v.w;
  }
  __syncthreads();
#pragma unroll
  for (int rep = 0; rep < 4; ++rep) {
    const int n = rep * 16 + (tid >> 4);
    const int k = (tid & 15) * 4;
    ushort4 o;
    o.x = f2bf(t[k + 0][n]);
    o.y = f2bf(t[k + 1][n]);
    o.z = f2bf(t[k + 2][n]);
    o.w = f2bf(t[k + 3][n]);
    *(ushort4*)(out + (size_t)(n0 + n) * K + k0 + k) = o;
  }
}

// bf16 MFMA GEMM: C = act(A@B + bias) [+ res]
template <int BM, int BN, int WM, int WN, bool GELU>
__global__ __launch_bounds__(256) void gemm_bf16(
    const unsigned short* __restrict__ A, const unsigned short* __restrict__ Bt,
    const float* __restrict__ bias, const float* __restrict__ res,
    float* __restrict__ Cf, unsigned short* __restrict__ Cb,
    int M, int N, int K) {
  constexpr int WCOLS = BN / WN;
  constexpr int LA = BM / 64;
  constexpr int LB = BN / 64;
  constexpr int MT = WM / 16;
  constexpr int NT = WN / 16;
  __shared__ __align__(16) unsigned short As[BM * 32];
  __shared__ __align__(16) unsigned short Bs[BN * 32];
  const int tid = threadIdx.x;
  const int wid = tid >> 6, lane = tid & 63;
  const int m0 = blockIdx.y * BM, n0 = blockIdx.x * BN;
  const int mbase = (wid / WCOLS) * WM, nbase = (wid % WCOLS) * WN;

  floatx4 acc[MT][NT];
#pragma unroll
  for (int i = 0; i < MT; ++i)
#pragma unroll
    for (int j = 0; j < NT; ++j) {
      floatx4 z = {0.f, 0.f, 0.f, 0.f};
      acc[i][j] = z;
    }

  const int srow = lane >> 2;
  const int scol = (lane & 3) * 8;
  const unsigned short* Ag = A + (size_t)m0 * K;
  const unsigned short* Bg = Bt + (size_t)n0 * K;
  const char* Ab = (const char*)As;
  const char* Bb = (const char*)Bs;
  const int fr = (lane & 15);
  const int fk = (lane >> 4) * 16;

  for (int k0 = 0; k0 < K; k0 += 32) {
    __syncthreads();
#pragma unroll
    for (int j = 0; j < LA; ++j) {
      const int strip = j * 4 + wid;
      __builtin_amdgcn_global_load_lds(
          AS1(Ag + (size_t)(strip * 16 + srow) * K + k0 + scol),
          AS3((char*)As + strip * 1024), 16, 0, 0);
    }
#pragma unroll
    for (int j = 0; j < LB; ++j) {
      const int strip = j * 4 + wid;
      __builtin_amdgcn_global_load_lds(
          AS1(Bg + (size_t)(strip * 16 + srow) * K + k0 + scol),
          AS3((char*)Bs + strip * 1024), 16, 0, 0);
    }
    __syncthreads();
    bf16x8 af[MT], bfr[NT];
#pragma unroll
    for (int i = 0; i < MT; ++i)
      af[i] = *(const bf16x8*)(Ab + (mbase + i * 16 + fr) * 64 + fk);
#pragma unroll
    for (int j = 0; j < NT; ++j)
      bfr[j] = *(const bf16x8*)(Bb + (nbase + j * 16 + fr) * 64 + fk);
#pragma unroll
    for (int i = 0; i < MT; ++i)
#pragma unroll
      for (int j = 0; j < NT; ++j)
        acc[i][j] = __builtin_amdgcn_mfma_f32_16x16x32_bf16(af[i], bfr[j],
                                                            acc[i][j], 0, 0, 0);
  }

  const int mr = (lane >> 4) * 4;
  const int nc = lane & 15;
#pragma unroll
  for (int i = 0; i < MT; ++i)
#pragma unroll
    for (int j = 0; j < NT; ++j) {
      const int n = n0 + nbase + j * 16 + nc;
      const float bv = bias[n];
#pragma unroll
      for (int r = 0; r < 4; ++r) {
        const int m = m0 + mbase + i * 16 + mr + r;
        float v = acc[i][j][r] + bv;
        if (GELU) v = gelu_f(v);
        if (res) v += res[(size_t)m * N + n];
        if (Cf) Cf[(size_t)m * N + n] = v;
        if (Cb) Cb[(size_t)m * N + n] = f2bf(v);
      }
    }
}

// Cosformer causal linear attention, MFMA flash-style.
// s_ij = (relu(q_i).relu(k_j)) * cos(pi/2*(i-j)/L), j<=i
// out_i = sum_j s_ij v_j / (sum_j s_ij + eps)
// Block: one 64-row i-tile of one (b,h); 4 waves x 16-row strips.
__global__ __launch_bounds__(256) void attn_mfma(const unsigned short* __restrict__ qkv,
                                                 unsigned short* __restrict__ out) {
  const int it = blockIdx.x;
  const int bh = blockIdx.y;
  const int b = bh >> 4, h = bh & 15;
  const int tid = threadIdx.x;
  const int w = tid >> 6, lane = tid & 63;
  const int qd = lane >> 4, ln = lane & 15;
  const int i0 = it * 64;
  __shared__ __align__(16) char sq[8192];   // Q' bf16 [i][d] swizzled
  __shared__ __align__(16) char sk[8192];   // K' bf16 [j][d] swizzled
  __shared__ __align__(16) char svt[8192];  // V^T bf16 [e][j] swizzled
  __shared__ __align__(16) char ss[8192];   // S bf16 [i][j] swizzled
  const unsigned short* base = qkv + (size_t)b * (TB_L * 3072) + h * 64;
  const float PH = 1.5339807878856412e-3f;  // pi/2/1024

  // stage Q' (relu on bf16 = clear if sign bit set)
#pragma unroll
  for (int p = 0; p < 2; ++p) {
    const int flat = p * 256 + tid;
    const int r = flat >> 3, c = flat & 7;
    u16x8 v = *(const u16x8*)(base + (size_t)(i0 + r) * 3072 + c * 8);
#pragma unroll
    for (int z = 0; z < 8; ++z) v[z] = (v[z] & 0x8000) ? (unsigned short)0 : v[z];
    *(u16x8*)(sq + swz(r, c * 16)) = v;
  }
  __syncthreads();

  bf16x8 aq[2];
#pragma unroll
  for (int ks = 0; ks < 2; ++ks)
    aq[ks] = *(const bf16x8*)(sq + swz(w * 16 + ln, ks * 64 + qd * 16));

  float ci[4], si[4];
#pragma unroll
  for (int r = 0; r < 4; ++r)
    __sincosf(PH * (float)(i0 + w * 16 + qd * 4 + r), &si[r], &ci[r]);

  floatx4 acc_o[4], acc_n;
  {
    floatx4 z = {0.f, 0.f, 0.f, 0.f};
#pragma unroll
    for (int nt = 0; nt < 4; ++nt) acc_o[nt] = z;
    acc_n = z;
  }
  bf16x8 ones;
#pragma unroll
  for (int z = 0; z < 8; ++z) ones[z] = (short)0x3F80;  // bf16 1.0

  for (int jt = 0; jt <= it; ++jt) {
    const int j0 = jt * 64;
    __syncthreads();  // all waves done reading previous sk/svt
#pragma unroll
    for (int p = 0; p < 2; ++p) {
      const int flat = p * 256 + tid;
      const int r = flat >> 3, c = flat & 7;
      u16x8 kv = *(const u16x8*)(base + (size_t)(j0 + r) * 3072 + 1024 + c * 8);
#pragma unroll
      for (int z = 0; z < 8; ++z) kv[z] = (kv[z] & 0x8000) ? (unsigned short)0 : kv[z];
      *(u16x8*)(sk + swz(r, c * 16)) = kv;
      u16x8 vv = *(const u16x8*)(base + (size_t)(j0 + r) * 3072 + 2048 + c * 8);
#pragma unroll
      for (int z = 0; z < 8; ++z)  // scatter-transpose: V[j][e] -> svt[e][j]
        *(unsigned short*)(svt + swz(c * 8 + z, r * 2)) = (unsigned short)vv[z];
    }
    __syncthreads();

    // S-strip = Q'K'^T (16 rows x 64 j per wave)
    floatx4 s_acc[4];
    {
      floatx4 z = {0.f, 0.f, 0.f, 0.f};
#pragma unroll
      for (int nt = 0; nt < 4; ++nt) s_acc[nt] = z;
    }
#pragma unroll
    for (int ks = 0; ks < 2; ++ks)
#pragma unroll
      for (int nt = 0; nt < 4; ++nt) {
        const bf16x8 bk = *(const bf16x8*)(sk + swz(nt * 16 + ln, ks * 64 + qd * 16));
        s_acc[nt] = __builtin_amdgcn_mfma_f32_16x16x32_bf16(aq[ks], bk, s_acc[nt], 0, 0, 0);
      }

    // cos weighting (exact, fp32): cos(ti-tj) = ci*cj + si*sj; mask diag; to LDS
    float cj[4], sj[4];
#pragma unroll
    for (int nt = 0; nt < 4; ++nt)
      __sincosf(PH * (float)(j0 + nt * 16 + ln), &sj[nt], &cj[nt]);
    const bool diag = (jt == it);
    const int li = w * 16 + qd * 4;
#pragma unroll
    for (int nt = 0; nt < 4; ++nt) {
      const int jl = nt * 16 + ln;
#pragma unroll
      for (int r = 0; r < 4; ++r) {
        float val = s_acc[nt][r] * (ci[r] * cj[nt] + si[r] * sj[nt]);
        if (diag && jl > li + r) val = 0.f;
        *(unsigned short*)(ss + swz(li + r, jl * 2)) = f2bf(val);
      }
    }

    // PV + norm (wave reads only its own ss rows -> no block sync needed)
#pragma unroll
    for (int ks = 0; ks < 2; ++ks) {
      const bf16x8 as = *(const bf16x8*)(ss + swz(w * 16 + ln, ks * 64 + qd * 16));
#pragma unroll
      for (int nt = 0; nt < 4; ++nt) {
        const bf16x8 bv = *(const bf16x8*)(svt + swz(nt * 16 + ln, ks * 64 + qd * 16));
        acc_o[nt] = __builtin_amdgcn_mfma_f32_16x16x32_bf16(as, bv, acc_o[nt], 0, 0, 0);
      }
      acc_n = __builtin_amdgcn_mfma_f32_16x16x32_bf16(as, ones, acc_n, 0, 0, 0);
    }
  }

#pragma unroll
  for (int r = 0; r < 4; ++r) {
    const float inv = 1.0f / (acc_n[r] + 1e-6f);
    unsigned short* op =
        out + (size_t)(b * TB_L + i0 + w * 16 + qd * 4 + r) * TB_E + h * 64;
#pragma unroll
    for (int nt = 0; nt < 4; ++nt) op[nt * 16 + ln] = f2bf(acc_o[nt][r] * inv);
  }
}

extern "C" void kernel_launch(void* const* d_in, const int* in_sizes, int n_in,
                              void* d_out, int out_size, void* d_ws, size_t ws_size,
                              hipStream_t stream) {
  const float* x     = (const float*)d_in[0];
  const float* qkv_w = (const float*)d_in[1];
  const float* qkv_b = (const float*)d_in[2];
  const float* out_w = (const float*)d_in[3];
  const float* out_b = (const float*)d_in[4];
  const float* n1w   = (const float*)d_in[5];
  const float* n2w   = (const float*)d_in[6];
  const float* w1    = (const float*)d_in[7];
  const float* b1    = (const float*)d_in[8];
  const float* w2    = (const float*)d_in[9];
  const float* b2    = (const float*)d_in[10];

  char* wsb = (char*)d_ws;
  unsigned short* qkvb  = (unsigned short*)wsb;
  unsigned short* g     = (unsigned short*)wsb;
  unsigned short* xnb   = (unsigned short*)(wsb + 16777216);
  unsigned short* attnb = (unsigned short*)(wsb + 20971520);
  float*          h     = (float*)(wsb + 25165824);
  unsigned short* qkvwt = (unsigned short*)(wsb + 33554432);
  unsigned short* outwt = (unsigned short*)(wsb + 39845888);
  unsigned short* w1t   = (unsigned short*)(wsb + 41943040);
  unsigned short* w2t   = (unsigned short*)(wsb + 50331648);
  float* out = (float*)d_out;
  const int M = 2048;

  transpose_bf16<<<dim3(3072 / 64, 1024 / 64), 256, 0, stream>>>(qkv_w, qkvwt, 1024, 3072);
  transpose_bf16<<<dim3(1024 / 64, 1024 / 64), 256, 0, stream>>>(out_w, outwt, 1024, 1024);
  transpose_bf16<<<dim3(4096 / 64, 1024 / 64), 256, 0, stream>>>(w1, w1t, 1024, 4096);
  transpose_bf16<<<dim3(1024 / 64, 4096 / 64), 256, 0, stream>>>(w2, w2t, 4096, 1024);

  rms_kernel<<<dim3(M), 256, 0, stream>>>(x, n1w, xnb);
  gemm_bf16<64, 128, 64, 32, false><<<dim3(3072 / 128, M / 64), 256, 0, stream>>>(
      xnb, qkvwt, qkv_b, nullptr, nullptr, qkvb, M, 3072, 1024);
  attn_mfma<<<dim3(16, 32), 256, 0, stream>>>(qkvb, attnb);
  gemm_bf16<64, 64, 32, 32, false><<<dim3(1024 / 64, M / 64), 256, 0, stream>>>(
      attnb, outwt, out_b, x, h, nullptr, M, 1024, 1024);
  rms_kernel<<<dim3(M), 256, 0, stream>>>(h, n2w, xnb);
  gemm_bf16<128, 128, 64, 64, true><<<dim3(4096 / 128, M / 128), 256, 0, stream>>>(
      xnb, w1t, b1, nullptr, nullptr, g, M, 4096, 1024);
  gemm_bf16<64, 64, 32, 32, false><<<dim3(1024 / 64, M / 64), 256, 0, stream>>>(
      g, w2t, b2, h, out, nullptr, M, 1024, 4096);
}